// Round 2
// baseline (194.988 us; speedup 1.0000x reference)
//
#include <hip/hip_runtime.h>
#include <hip/hip_bf16.h>

// BEV bilinear feature extraction.
// feats: (B=4, C=256, H=188, W=188) f32
// centers: (B=4, N=500, 3) f32
// out: (B, N, C) f32
//
// One block per PAIR of points; threadIdx.x = channel. Each thread gathers
// the 4 bilinear corners for its channel for 2 points (8 independent loads
// in flight -> better latency hiding on the inherent (B,C,H,W) gather),
// then writes 2 coalesced outputs.

constexpr int B = 4;
constexpr int C = 256;
constexpr int H = 188;
constexpr int W = 188;
constexpr int N = 500;

__device__ __forceinline__ void point_setup(
    const float* __restrict__ centers, int pt,
    int& b, long& base_off, float& wa, float& wb, float& wc, float& wd,
    int& i00, int& i10, int& i01, int& i11)
{
    b = pt / N;
    const float cx = centers[pt * 3 + 0];
    const float cy = centers[pt * 3 + 1];

    // Match reference numerics: (c - PC_START) / VOXEL / OUT_STRIDE
    const float x = (cx - (-75.2f)) / 0.1f / 8.0f;
    const float y = (cy - (-75.2f)) / 0.1f / 8.0f;

    // Clamp BEFORE weight computation (torch/reference semantics).
    const int xf = (int)floorf(x);
    const int yf = (int)floorf(y);
    const int x0 = min(max(xf,     0), W - 1);
    const int x1 = min(max(xf + 1, 0), W - 1);
    const int y0 = min(max(yf,     0), H - 1);
    const int y1 = min(max(yf + 1, 0), H - 1);

    const float x0f = (float)x0, x1f = (float)x1;
    const float y0f = (float)y0, y1f = (float)y1;
    wa = (x1f - x) * (y1f - y);
    wb = (x1f - x) * (y  - y0f);
    wc = (x  - x0f) * (y1f - y);
    wd = (x  - x0f) * (y  - y0f);

    i00 = y0 * W + x0;
    i10 = y1 * W + x0;
    i01 = y0 * W + x1;
    i11 = y1 * W + x1;
    base_off = (long)b * C * H * W;
}

__global__ __launch_bounds__(256) void bev_extract_kernel(
    const float* __restrict__ feats,
    const float* __restrict__ centers,
    float* __restrict__ out)
{
    const int c   = threadIdx.x;          // channel
    const int pt0 = blockIdx.x * 2;       // two points per block
    const int pt1 = pt0 + 1;

    int b0, b1;
    long bo0, bo1;
    float wa0, wb0, wc0, wd0, wa1, wb1, wc1, wd1;
    int a00, a10, a01, a11, e00, e10, e01, e11;
    point_setup(centers, pt0, b0, bo0, wa0, wb0, wc0, wd0, a00, a10, a01, a11);
    point_setup(centers, pt1, b1, bo1, wa1, wb1, wc1, wd1, e00, e10, e01, e11);

    const float* p0 = feats + bo0 + (long)c * (H * W);
    const float* p1 = feats + bo1 + (long)c * (H * W);

    // 8 independent gather loads in flight.
    const float Ia0 = p0[a00];
    const float Ib0 = p0[a10];
    const float Ic0 = p0[a01];
    const float Id0 = p0[a11];
    const float Ia1 = p1[e00];
    const float Ib1 = p1[e10];
    const float Ic1 = p1[e01];
    const float Id1 = p1[e11];

    out[(long)pt0 * C + c] = Ia0 * wa0 + Ib0 * wb0 + Ic0 * wc0 + Id0 * wd0;
    out[(long)pt1 * C + c] = Ia1 * wa1 + Ib1 * wb1 + Ic1 * wc1 + Id1 * wd1;
}

extern "C" void kernel_launch(void* const* d_in, const int* in_sizes, int n_in,
                              void* d_out, int out_size, void* d_ws, size_t ws_size,
                              hipStream_t stream)
{
    const float* feats   = (const float*)d_in[0];  // (B, C, H, W)
    const float* centers = (const float*)d_in[1];  // (B, N, 3)
    float* out = (float*)d_out;                    // (B, N, C)

    dim3 grid((B * N) / 2);   // 1000 blocks, 2 points each
    dim3 block(C);            // 256 threads = channels
    bev_extract_kernel<<<grid, block, 0, stream>>>(feats, centers, out);
}